// Round 14
// baseline (587.247 us; speedup 1.0000x reference)
//
#include <hip/hip_runtime.h>
#include <hip/hip_bf16.h>

#define DD 128
#define NKEY8 8      // keys per dst = R
#define LDA_AGG 1056 // 1024 + 32 pad (non-pow2 row stride)
#define SRCM 0x00FFFFFF

using bf16x8 = __attribute__((ext_vector_type(8))) __bf16;
using f32x4  = __attribute__((ext_vector_type(4))) float;

__device__ __forceinline__ float leaky(float x, float s){ return x > 0.f ? x : s * x; }
__device__ __forceinline__ float bflo(unsigned u){ return __uint_as_float(u << 16); }
__device__ __forceinline__ float bfhi(unsigned u){ return __uint_as_float(u & 0xffff0000u); }
__device__ __forceinline__ unsigned bfpack(float x, float y){
  __hip_bfloat16 hx = __float2bfloat16(x), hy = __float2bfloat16(y);
  unsigned short ux = *reinterpret_cast<unsigned short*>(&hx);
  unsigned short uy = *reinterpret_cast<unsigned short*>(&hy);
  return (unsigned)ux | ((unsigned)uy << 16);
}

// ---------------- CSR build (counting sort by key = dst*8 + etype) ----------------
__global__ void k_hist(const int* __restrict__ dst, const int* __restrict__ et,
                       int* __restrict__ cnt, int E_){
  int e = blockIdx.x * 256 + threadIdx.x;
  if (e < E_) atomicAdd(&cnt[dst[e] * NKEY8 + et[e]], 1);
}

__global__ void k_scan1(const int* __restrict__ cnt, int* __restrict__ ptr,
                        int* __restrict__ part, int n){
  __shared__ int sm[256];
  int tid = threadIdx.x;
  int base = blockIdx.x * 1024 + tid * 4;
  int a0 = base + 0 < n ? cnt[base + 0] : 0;
  int a1 = base + 1 < n ? cnt[base + 1] : 0;
  int a2 = base + 2 < n ? cnt[base + 2] : 0;
  int a3 = base + 3 < n ? cnt[base + 3] : 0;
  int s = a0 + a1 + a2 + a3;
  sm[tid] = s; __syncthreads();
  for (int off = 1; off < 256; off <<= 1){
    int v = tid >= off ? sm[tid - off] : 0;
    __syncthreads(); sm[tid] += v; __syncthreads();
  }
  int ex = sm[tid] - s;
  if (tid == 255) part[blockIdx.x] = sm[255];
  if (base + 0 < n) ptr[base + 0] = ex;
  if (base + 1 < n) ptr[base + 1] = ex + a0;
  if (base + 2 < n) ptr[base + 2] = ex + a0 + a1;
  if (base + 3 < n) ptr[base + 3] = ex + a0 + a1 + a2;
}

__global__ void k_scan2(int* __restrict__ part, int nb){  // single block, 512 thr
  __shared__ int sm[512];
  int tid = threadIdx.x;
  int v = tid < nb ? part[tid] : 0;
  sm[tid] = v; __syncthreads();
  for (int off = 1; off < 512; off <<= 1){
    int u = tid >= off ? sm[tid - off] : 0;
    __syncthreads(); sm[tid] += u; __syncthreads();
  }
  if (tid < nb) part[tid] = sm[tid] - v;  // exclusive
}

__global__ void k_scan3(int* __restrict__ ptr, const int* __restrict__ part, int n, int E_){
  int i = blockIdx.x * 256 + threadIdx.x;
  if (i < n) ptr[i] += part[i >> 10];
  if (i == n) ptr[n] = E_;
}

// inv + init run (= ptr) in one pass
__global__ void k_inv(const int* __restrict__ ptr, float* __restrict__ inv,
                      int* __restrict__ run, int n){
  int i = blockIdx.x * 256 + threadIdx.x;
  if (i < n){
    int p = ptr[i];
    inv[i] = 1.0f / fmaxf((float)(ptr[i + 1] - p), 1.0f);
    run[i] = p;
  }
}

// epk[pos] = (etype << 24) | src   (sorted by (dst, etype))
__global__ void k_scatter_pos(const int* __restrict__ src, const int* __restrict__ dst,
                              const int* __restrict__ et, int* __restrict__ run,
                              int* __restrict__ epk, int E_){
  int e = blockIdx.x * 256 + threadIdx.x;
  if (e >= E_) return;
  int r = et[e];
  int pos = atomicAdd(&run[dst[e] * NKEY8 + r], 1);
  epk[pos] = (r << 24) | src[e];
}

__global__ void k_cvt(const float* __restrict__ in, __hip_bfloat16* __restrict__ out, int n){
  int i = blockIdx.x * 256 + threadIdx.x;
  if (i < n) out[i] = __float2bfloat16(in[i]);
}

// ---------------- weights: combine + pack into MFMA B-fragment order ----------------
__global__ void k_makeW(const float* __restrict__ basis, const float* __restrict__ comp,
                        const float* __restrict__ root, __hip_bfloat16* __restrict__ Wp){
  int idx = blockIdx.x * 256 + threadIdx.x;   // k*128 + n, k in [0,1152)
  int k = idx >> 7, n = idx & 127;
  float v;
  if (k < 1024){
    int r = k >> 7, i = k & 127;
    float s = 0.f;
    #pragma unroll
    for (int b = 0; b < 8; b++) s += comp[r * 8 + b] * basis[b * 16384 + i * 128 + n];
    v = s;
  } else {
    v = root[(k - 1024) * 128 + n];
  }
  int kt = k >> 5, kr = k & 31;
  int lane = (n & 15) | ((kr >> 3) << 4);
  int ii = kr & 7, nt = n >> 4;
  Wp[((size_t)(kt * 8 + nt) * 64 + lane) * 8 + ii] = __float2bfloat16(v);
}

// Wstack[h*128+i][n] = Wg[i][h*128+n], packed (ntt=8)
__global__ void k_packGZ(const float* __restrict__ Wg, __hip_bfloat16* __restrict__ Wp){
  int idx = blockIdx.x * 256 + threadIdx.x;   // k*128 + n, k in [0,512)
  int k = idx >> 7, n = idx & 127;
  int h = k >> 7, i = k & 127;
  float v = Wg[(size_t)i * 512 + h * 128 + n];
  int kt = k >> 5, kr = k & 31;
  int lane = (n & 15) | ((kr >> 3) << 4);
  int ii = kr & 7, nt = n >> 4;
  Wp[((size_t)(kt * 8 + nt) * 64 + lane) * 8 + ii] = __float2bfloat16(v);
}

// vT[sd][h][i] = sum_o Wg[i, h*128+o] * a_{src/dst}[h,o]
__global__ void k_valpha(const float* __restrict__ Wg, const float* __restrict__ a_src,
                         const float* __restrict__ a_dst, float* __restrict__ vT){
  int id = blockIdx.x * 256 + threadIdx.x;   // [0,1024)
  int sd = id >> 9, h = (id >> 7) & 3, i = id & 127;
  const float* a = (sd ? a_dst : a_src) + h * 128;
  const float* w = Wg + (size_t)i * 512 + h * 128;
  float s = 0.f;
  #pragma unroll 4
  for (int o = 0; o < 128; o++) s += w[o] * a[o];
  vT[(size_t)sd * 512 + h * 128 + i] = s;
}

// aS/aD from x directly: wave per node, 16 lanes per head
__global__ void k_av(const __hip_bfloat16* __restrict__ xb, const float* __restrict__ vT,
                     float* __restrict__ aS, float* __restrict__ aD, int N_){
  int node = blockIdx.x * 4 + (threadIdx.x >> 6);
  if (node >= N_) return;
  int lane = threadIdx.x & 63;
  int h = lane >> 4, dg = lane & 15;
  uint4 u = *(const uint4*)(xb + (size_t)node * DD + dg * 8);
  const float* vs = vT + h * 128 + dg * 8;
  const float* vd = vT + 512 + h * 128 + dg * 8;
  float ss = 0.f, sd = 0.f;
  #pragma unroll
  for (int w = 0; w < 4; w++){
    unsigned uw = ((const unsigned*)&u)[w];
    float f0 = bflo(uw), f1 = bfhi(uw);
    ss += f0 * vs[w * 2] + f1 * vs[w * 2 + 1];
    sd += f0 * vd[w * 2] + f1 * vd[w * 2 + 1];
  }
  for (int o = 1; o < 16; o <<= 1){ ss += __shfl_xor(ss, o); sd += __shfl_xor(sd, o); }
  if (dg == 0){ aS[(size_t)node * 4 + h] = ss; aD[(size_t)node * 4 + h] = sd; }
}

// ---------------- RGCN: CSR aggregation, half-wave-per-dst, 8-deep batch ----------------
__global__ void k_csr_agg(const int* __restrict__ ptr, const int* __restrict__ epk,
                          const float* __restrict__ inv, const __hip_bfloat16* __restrict__ xb,
                          __hip_bfloat16* __restrict__ agg, int N_){
  int w = threadIdx.x >> 6, lane = threadIdx.x & 63;
  int hw = lane >> 5, sl = lane & 31;
  int t = blockIdx.x * 8 + w * 2 + hw;
  if (t >= N_) return;
  int beg = ptr[t * 8], end = ptr[t * 8 + 8];
  const __hip_bfloat16* xcol = xb + sl * 4;
  __hip_bfloat16* aggrow = agg + (size_t)t * LDA_AGG + sl * 4;
  const float* invrow = inv + (size_t)t * 8;
  float a0 = 0.f, a1 = 0.f, a2 = 0.f, a3 = 0.f;
  int cur = -1;
  unsigned written = 0;

#define CSR_FLUSH() { float iv = invrow[cur]; \
    uint2 o_; o_.x = bfpack(a0 * iv, a1 * iv); o_.y = bfpack(a2 * iv, a3 * iv); \
    *(uint2*)(aggrow + cur * 128) = o_; written |= (1u << cur); }
#define CSR_PROC(PK, U) { int r_ = (PK) >> 24; \
    if (r_ != cur){ if (cur >= 0){ CSR_FLUSH(); } cur = r_; a0 = a1 = a2 = a3 = 0.f; } \
    a0 += bflo((U).x); a1 += bfhi((U).x); a2 += bflo((U).y); a3 += bfhi((U).y); }

  int e = beg;
  for (; e + 8 <= end; e += 8){
    int pk0 = epk[e],     pk1 = epk[e + 1], pk2 = epk[e + 2], pk3 = epk[e + 3];
    int pk4 = epk[e + 4], pk5 = epk[e + 5], pk6 = epk[e + 6], pk7 = epk[e + 7];
    uint2 u0 = *(const uint2*)(xcol + (size_t)(pk0 & SRCM) * DD);
    uint2 u1 = *(const uint2*)(xcol + (size_t)(pk1 & SRCM) * DD);
    uint2 u2 = *(const uint2*)(xcol + (size_t)(pk2 & SRCM) * DD);
    uint2 u3 = *(const uint2*)(xcol + (size_t)(pk3 & SRCM) * DD);
    uint2 u4 = *(const uint2*)(xcol + (size_t)(pk4 & SRCM) * DD);
    uint2 u5 = *(const uint2*)(xcol + (size_t)(pk5 & SRCM) * DD);
    uint2 u6 = *(const uint2*)(xcol + (size_t)(pk6 & SRCM) * DD);
    uint2 u7 = *(const uint2*)(xcol + (size_t)(pk7 & SRCM) * DD);
    CSR_PROC(pk0, u0); CSR_PROC(pk1, u1); CSR_PROC(pk2, u2); CSR_PROC(pk3, u3);
    CSR_PROC(pk4, u4); CSR_PROC(pk5, u5); CSR_PROC(pk6, u6); CSR_PROC(pk7, u7);
  }
  for (; e + 4 <= end; e += 4){
    int pk0 = epk[e], pk1 = epk[e + 1], pk2 = epk[e + 2], pk3 = epk[e + 3];
    uint2 u0 = *(const uint2*)(xcol + (size_t)(pk0 & SRCM) * DD);
    uint2 u1 = *(const uint2*)(xcol + (size_t)(pk1 & SRCM) * DD);
    uint2 u2 = *(const uint2*)(xcol + (size_t)(pk2 & SRCM) * DD);
    uint2 u3 = *(const uint2*)(xcol + (size_t)(pk3 & SRCM) * DD);
    CSR_PROC(pk0, u0); CSR_PROC(pk1, u1); CSR_PROC(pk2, u2); CSR_PROC(pk3, u3);
  }
  for (; e < end; e++){
    int pk0 = epk[e];
    uint2 u0 = *(const uint2*)(xcol + (size_t)(pk0 & SRCM) * DD);
    CSR_PROC(pk0, u0);
  }
  if (cur >= 0){ CSR_FLUSH(); }
  uint2 z_; z_.x = 0u; z_.y = 0u;
  #pragma unroll
  for (int r = 0; r < 8; r++)
    if (!(written & (1u << r))) *(uint2*)(aggrow + r * 128) = z_;
#undef CSR_PROC
#undef CSR_FLUSH
}

// ---------------- GAT: coef-weighted aggregation of x into z[N,512], 4-deep ----------------
__global__ void k_zagg(const int* __restrict__ ptr, const int* __restrict__ epk,
                       const float* __restrict__ cf, const float* __restrict__ cfS,
                       const float* __restrict__ den, const __hip_bfloat16* __restrict__ xb,
                       __hip_bfloat16* __restrict__ z, int N_){
  int w = threadIdx.x >> 6, lane = threadIdx.x & 63;
  int t = blockIdx.x * 4 + w;
  if (t >= N_) return;
  int dg = lane & 31, ep = lane >> 5;
  int beg = ptr[t * 8], end = ptr[t * 8 + 8];
  float acc[4][4];
  #pragma unroll
  for (int h = 0; h < 4; h++)
    #pragma unroll
    for (int j = 0; j < 4; j++) acc[h][j] = 0.f;
  const __hip_bfloat16* xbase = xb + dg * 4;

#define ZPROC(V, C) { \
    float f0 = bflo((V).x), f1 = bfhi((V).x), f2 = bflo((V).y), f3 = bfhi((V).y); \
    const float* cp = (const float*)&(C); \
    _Pragma("unroll") \
    for (int h = 0; h < 4; h++){ \
      acc[h][0] += cp[h] * f0; acc[h][1] += cp[h] * f1; \
      acc[h][2] += cp[h] * f2; acc[h][3] += cp[h] * f3; } }

  int e = beg + ep;
  for (; e + 6 < end; e += 8){
    int s0 = epk[e] & SRCM,     s1 = epk[e + 2] & SRCM;
    int s2 = epk[e + 4] & SRCM, s3 = epk[e + 6] & SRCM;
    uint2 v0 = *(const uint2*)(xbase + (size_t)s0 * DD);
    uint2 v1 = *(const uint2*)(xbase + (size_t)s1 * DD);
    uint2 v2 = *(const uint2*)(xbase + (size_t)s2 * DD);
    uint2 v3 = *(const uint2*)(xbase + (size_t)s3 * DD);
    float4 c0 = *(const float4*)(cf + (size_t)e * 4);
    float4 c1 = *(const float4*)(cf + (size_t)(e + 2) * 4);
    float4 c2 = *(const float4*)(cf + (size_t)(e + 4) * 4);
    float4 c3 = *(const float4*)(cf + (size_t)(e + 6) * 4);
    ZPROC(v0, c0); ZPROC(v1, c1); ZPROC(v2, c2); ZPROC(v3, c3);
  }
  for (; e < end; e += 2){
    int s = epk[e] & SRCM;
    uint2 v = *(const uint2*)(xbase + (size_t)s * DD);
    float4 c = *(const float4*)(cf + (size_t)e * 4);
    ZPROC(v, c);
  }
#undef ZPROC
  #pragma unroll
  for (int h = 0; h < 4; h++)
    #pragma unroll
    for (int j = 0; j < 4; j++) acc[h][j] += __shfl_xor(acc[h][j], 32);
  if (ep == 0){
    uint2 v = *(const uint2*)(xbase + (size_t)t * DD);
    float f0 = bflo(v.x), f1 = bfhi(v.x), f2 = bflo(v.y), f3 = bfhi(v.y);
    float4 cs = *(const float4*)(cfS + (size_t)t * 4);
    float4 dn = *(const float4*)(den + (size_t)t * 4);
    const float* csp = (const float*)&cs;
    const float* dnp = (const float*)&dn;
    #pragma unroll
    for (int h = 0; h < 4; h++){
      float sc = 0.25f / dnp[h];
      float y0 = (acc[h][0] + csp[h] * f0) * sc;
      float y1 = (acc[h][1] + csp[h] * f1) * sc;
      float y2 = (acc[h][2] + csp[h] * f2) * sc;
      float y3 = (acc[h][3] + csp[h] * f3) * sc;
      uint2 o; o.x = bfpack(y0, y1); o.y = bfpack(y2, y3);
      *(uint2*)(z + (size_t)t * 512 + h * 128 + dg * 4) = o;
    }
  }
}

// ---------------- MFMA GEMM, 128-row tiles, 2x ktile unroll, split-A, fused epilogues ------
// MODE 1: Cb = leaky(LN(acc+bias)).  MODE 3: Cf = L2normalize(acc+bias).
// K1, K2 must be multiples of 64 (1024/512/128 here).
template<int MODE>
__launch_bounds__(256)
__global__ void k_gemm_mfma(const __hip_bfloat16* __restrict__ A1, int lda1, int K1,
                            const __hip_bfloat16* __restrict__ A2, int K2,
                            int M, const __hip_bfloat16* __restrict__ Bp, int ntt,
                            const float* __restrict__ bias,
                            const float* __restrict__ ln_g, const float* __restrict__ ln_b,
                            float* __restrict__ Cf, __hip_bfloat16* __restrict__ Cb,
                            int ldc){
  int wave = threadIdx.x >> 6, lane = threadIdx.x & 63;
  int nt0 = blockIdx.y << 3;
  int mbase = blockIdx.x * 128 + wave * 32;
  int r0 = min(mbase + (lane & 15), M - 1);
  int r1 = min(mbase + 16 + (lane & 15), M - 1);
  int koff = (lane >> 4) << 3;
  f32x4 acc[2][8];
  #pragma unroll
  for (int i = 0; i < 2; i++)
    #pragma unroll
    for (int j = 0; j < 8; j++) acc[i][j] = (f32x4){0.f, 0.f, 0.f, 0.f};

  int ktile = 0;
  {
    const __hip_bfloat16* a0p = A1 + (size_t)r0 * lda1 + koff;
    const __hip_bfloat16* a1p = A1 + (size_t)r1 * lda1 + koff;
    for (int k0 = 0; k0 + 64 <= K1; k0 += 64, ktile += 2){
      bf16x8 aA0 = *(const bf16x8*)(a0p + k0);
      bf16x8 aB0 = *(const bf16x8*)(a1p + k0);
      bf16x8 aA1 = *(const bf16x8*)(a0p + k0 + 32);
      bf16x8 aB1 = *(const bf16x8*)(a1p + k0 + 32);
      const bf16x8* bfr0 = (const bf16x8*)(Bp + (((size_t)ktile * ntt + nt0) * 64 + lane) * 8);
      const bf16x8* bfr1 = (const bf16x8*)(Bp + (((size_t)(ktile + 1) * ntt + nt0) * 64 + lane) * 8);
      #pragma unroll
      for (int nt = 0; nt < 8; nt++){
        bf16x8 b = bfr0[(size_t)nt * 64];
        acc[0][nt] = __builtin_amdgcn_mfma_f32_16x16x32_bf16(aA0, b, acc[0][nt], 0, 0, 0);
        acc[1][nt] = __builtin_amdgcn_mfma_f32_16x16x32_bf16(aB0, b, acc[1][nt], 0, 0, 0);
      }
      #pragma unroll
      for (int nt = 0; nt < 8; nt++){
        bf16x8 b = bfr1[(size_t)nt * 64];
        acc[0][nt] = __builtin_amdgcn_mfma_f32_16x16x32_bf16(aA1, b, acc[0][nt], 0, 0, 0);
        acc[1][nt] = __builtin_amdgcn_mfma_f32_16x16x32_bf16(aB1, b, acc[1][nt], 0, 0, 0);
      }
    }
  }
  if (A2){
    const __hip_bfloat16* a0p = A2 + (size_t)r0 * DD + koff;
    const __hip_bfloat16* a1p = A2 + (size_t)r1 * DD + koff;
    for (int k0 = 0; k0 + 64 <= K2; k0 += 64, ktile += 2){
      bf16x8 aA0 = *(const bf16x8*)(a0p + k0);
      bf16x8 aB0 = *(const bf16x8*)(a1p + k0);
      bf16x8 aA1 = *(const bf16x8*)(a0p + k0 + 32);
      bf16x8 aB1 = *(const bf16x8*)(a1p + k0 + 32);
      const bf16x8* bfr0 = (const bf16x8*)(Bp + (((size_t)ktile * ntt + nt0) * 64 + lane) * 8);
      const bf16x8* bfr1 = (const bf16x8*)(Bp + (((size_t)(ktile + 1) * ntt + nt0) * 64 + lane) * 8);
      #pragma unroll
      for (int nt = 0; nt < 8; nt++){
        bf16x8 b = bfr0[(size_t)nt * 64];
        acc[0][nt] = __builtin_amdgcn_mfma_f32_16x16x32_bf16(aA0, b, acc[0][nt], 0, 0, 0);
        acc[1][nt] = __builtin_amdgcn_mfma_f32_16x16x32_bf16(aB0, b, acc[1][nt], 0, 0, 0);
      }
      #pragma unroll
      for (int nt = 0; nt < 8; nt++){
        bf16x8 b = bfr1[(size_t)nt * 64];
        acc[0][nt] = __builtin_amdgcn_mfma_f32_16x16x32_bf16(aA1, b, acc[0][nt], 0, 0, 0);
        acc[1][nt] = __builtin_amdgcn_mfma_f32_16x16x32_bf16(aB1, b, acc[1][nt], 0, 0, 0);
      }
    }
  }

  const int colb = lane & 15;
  const int lq = lane >> 4;

  float bias8[8], g8[8], b8[8];
  #pragma unroll
  for (int nt = 0; nt < 8; nt++){
    int c = (nt << 4) + colb;
    bias8[nt] = bias ? bias[c] : 0.f;
    if (MODE == 1){ g8[nt] = ln_g[c]; b8[nt] = ln_b[c]; }
  }

  #pragma unroll
  for (int mt = 0; mt < 2; mt++){
    #pragma unroll
    for (int j = 0; j < 4; j++){
      int row = mbase + mt * 16 + lq * 4 + j;
      if (MODE == 1){
        float v[8]; float s = 0.f;
        #pragma unroll
        for (int nt = 0; nt < 8; nt++){ v[nt] = acc[mt][nt][j] + bias8[nt]; s += v[nt]; }
        #pragma unroll
        for (int o = 1; o < 16; o <<= 1) s += __shfl_xor(s, o);
        float mu = s * (1.f / 128.f);
        float q = 0.f;
        #pragma unroll
        for (int nt = 0; nt < 8; nt++){ float dd = v[nt] - mu; q += dd * dd; }
        #pragma unroll
        for (int o = 1; o < 16; o <<= 1) q += __shfl_xor(q, o);
        float rstd = rsqrtf(q * (1.f / 128.f) + 1e-5f);
        if (row < M){
          #pragma unroll
          for (int nt = 0; nt < 8; nt++){
            float y = leaky((v[nt] - mu) * rstd * g8[nt] + b8[nt], 0.1f);
            Cb[(size_t)row * ldc + (nt << 4) + colb] = __float2bfloat16(y);
          }
        }
      } else { // MODE 3: bias + L2 normalize, fp32 out
        float v[8]; float q = 0.f;
        #pragma unroll
        for (int nt = 0; nt < 8; nt++){ v[nt] = acc[mt][nt][j] + bias8[nt]; q += v[nt] * v[nt]; }
        #pragma unroll
        for (int o = 1; o < 16; o <<= 1) q += __shfl_xor(q, o);
        float sc = 1.0f / fmaxf(sqrtf(q), 1e-12f);
        if (row < M){
          #pragma unroll
          for (int nt = 0; nt < 8; nt++)
            Cf[(size_t)row * ldc + (nt << 4) + colb] = v[nt] * sc;
        }
      }
    }
  }
}

// ---------------- GAT: per-(dst,head) softmax coefficients ----------------
__global__ void k_gat_coef(const int* __restrict__ ptr, const int* __restrict__ epk,
                           const float* __restrict__ aS, const float* __restrict__ aD,
                           float* __restrict__ cf, float* __restrict__ cfS,
                           float* __restrict__ den, int N_){
  int id = blockIdx.x * 256 + threadIdx.x;
  int t = id >> 2, h = id & 3;
  if (t >= N_) return;
  int beg = ptr[t * 8], end = ptr[t * 8 + 8];
  float adh = aD[(size_t)t * 4 + h];
  float ash = aS[(size_t)t * 4 + h];
  float selfe = leaky(ash + adh, 0.2f);
  float m = selfe;
  for (int e = beg; e < end; e++){
    int s = epk[e] & SRCM;
    float l = leaky(aS[(size_t)s * 4 + h] + adh, 0.2f);
    cf[(size_t)e * 4 + h] = l;
    m = fmaxf(m, l);
  }
  float sv = __expf(selfe - m);
  cfS[(size_t)t * 4 + h] = sv;
  float d = sv;
  for (int e = beg; e < end; e++){
    float x = __expf(cf[(size_t)e * 4 + h] - m);
    cf[(size_t)e * 4 + h] = x;
    d += x;
  }
  den[(size_t)t * 4 + h] = d;
}

extern "C" void kernel_launch(void* const* d_in, const int* in_sizes, int n_in,
                              void* d_out, int out_size, void* d_ws, size_t ws_size,
                              hipStream_t stream){
  const float* x       = (const float*)d_in[0];
  const int*   ei      = (const int*)d_in[1];
  const int*   et      = (const int*)d_in[2];
  const float* r0_basis= (const float*)d_in[3];  const float* r0_comp = (const float*)d_in[4];
  const float* r0_root = (const float*)d_in[5];  const float* r0_bias = (const float*)d_in[6];
  const float* ln0_g   = (const float*)d_in[7];  const float* ln0_b   = (const float*)d_in[8];
  const float* r1_basis= (const float*)d_in[9];  const float* r1_comp = (const float*)d_in[10];
  const float* r1_root = (const float*)d_in[11]; const float* r1_bias = (const float*)d_in[12];
  const float* ln1_g   = (const float*)d_in[13]; const float* ln1_b   = (const float*)d_in[14];
  const float* gat_w   = (const float*)d_in[15]; const float* gat_asrc= (const float*)d_in[16];
  const float* gat_adst= (const float*)d_in[17]; const float* gat_bias= (const float*)d_in[18];
  const float* ln2_g   = (const float*)d_in[19]; const float* ln2_b   = (const float*)d_in[20];
  const float* r2_basis= (const float*)d_in[21]; const float* r2_comp = (const float*)d_in[22];
  const float* r2_root = (const float*)d_in[23]; const float* r2_bias = (const float*)d_in[24];

  const int N_ = in_sizes[0] / DD;
  const int E_ = in_sizes[2];
  const int NK = N_ * NKEY8;
  const int* src = ei;
  const int* dst = ei + E_;
  float* T2 = (float*)d_out;

  char* wp_ = (char*)d_ws;
  auto alloc = [&](size_t b)->void*{ void* p = wp_; wp_ += (b + 255) & ~(size_t)255; return p; };
  __hip_bfloat16* agg16 = (__hip_bfloat16*)alloc((size_t)N_ * LDA_AGG * 2);  // also hosts z16
  __hip_bfloat16* xb16  = (__hip_bfloat16*)alloc((size_t)N_ * DD * 2);
  float*          inv   = (float*)alloc((size_t)NK * 4);
  int*            ptrb  = (int*)alloc((size_t)(NK + 1) * 4);
  int*            cnt   = (int*)alloc((size_t)NK * 4);
  int*            run   = (int*)alloc((size_t)NK * 4);
  int*            epk   = (int*)alloc((size_t)E_ * 4);
  int*            part  = (int*)alloc(512 * 4);
  float*          aS    = (float*)alloc((size_t)N_ * 4 * 4);
  float*          aD    = (float*)alloc((size_t)N_ * 4 * 4);
  float*          cf    = (float*)alloc((size_t)E_ * 4 * 4);
  float*          cfS   = (float*)alloc((size_t)N_ * 4 * 4);
  float*          den   = (float*)alloc((size_t)N_ * 4 * 4);
  float*          vT    = (float*)alloc((size_t)2 * 512 * 4);
  __hip_bfloat16* Wp    = (__hip_bfloat16*)alloc((size_t)1152 * 128 * 2);
  __hip_bfloat16* WpZ   = (__hip_bfloat16*)alloc((size_t)512 * 128 * 2);
  if ((size_t)(wp_ - (char*)d_ws) > ws_size) return;
  __hip_bfloat16* z16 = agg16;   // aliased: agg dead when z is live, and vice versa

  const int Mb = (N_ + 127) / 128;
  const int nScanB = (NK + 1023) / 1024;

  // ---- CSR build (same graph for all layers) ----
  hipMemsetAsync(cnt, 0, (size_t)NK * 4, stream);
  k_hist<<<(E_ + 255) / 256, 256, 0, stream>>>(dst, et, cnt, E_);
  k_scan1<<<nScanB, 256, 0, stream>>>(cnt, ptrb, part, NK);
  k_scan2<<<1, 512, 0, stream>>>(part, nScanB);
  k_scan3<<<(NK + 1 + 255) / 256, 256, 0, stream>>>(ptrb, part, NK, E_);
  k_inv<<<(NK + 255) / 256, 256, 0, stream>>>(ptrb, inv, run, NK);
  k_scatter_pos<<<(E_ + 255) / 256, 256, 0, stream>>>(src, dst, et, run, epk, E_);
  k_cvt<<<(N_ * DD + 255) / 256, 256, 0, stream>>>(x, xb16, N_ * DD);

  // ---- RGCN layer 0 (LN0+leaky fused) ----
  k_makeW<<<576, 256, 0, stream>>>(r0_basis, r0_comp, r0_root, Wp);
  k_csr_agg<<<(N_ + 7) / 8, 256, 0, stream>>>(ptrb, epk, inv, xb16, agg16, N_);
  k_gemm_mfma<1><<<dim3(Mb, 1), 256, 0, stream>>>(agg16, LDA_AGG, 1024, xb16, 128, N_, Wp, 8,
      r0_bias, ln0_g, ln0_b, nullptr, xb16, DD);

  // ---- RGCN layer 1 (LN1+leaky fused) ----
  k_makeW<<<576, 256, 0, stream>>>(r1_basis, r1_comp, r1_root, Wp);
  k_csr_agg<<<(N_ + 7) / 8, 256, 0, stream>>>(ptrb, epk, inv, xb16, agg16, N_);
  k_gemm_mfma<1><<<dim3(Mb, 1), 256, 0, stream>>>(agg16, LDA_AGG, 1024, xb16, 128, N_, Wp, 8,
      r1_bias, ln1_g, ln1_b, nullptr, xb16, DD);

  // ---- GAT: logits from x (no hH), coef, z-aggregate, K=512 GEMM (+bias+LN2 fused) ----
  k_valpha<<<4, 256, 0, stream>>>(gat_w, gat_asrc, gat_adst, vT);
  k_packGZ<<<256, 256, 0, stream>>>(gat_w, WpZ);
  k_av<<<(N_ + 3) / 4, 256, 0, stream>>>(xb16, vT, aS, aD, N_);
  k_gat_coef<<<(N_ * 4 + 255) / 256, 256, 0, stream>>>(ptrb, epk, aS, aD, cf, cfS, den, N_);
  k_zagg<<<(N_ + 3) / 4, 256, 0, stream>>>(ptrb, epk, cf, cfS, den, xb16, z16, N_);
  k_gemm_mfma<1><<<dim3(Mb, 1), 256, 0, stream>>>(z16, 512, 512, nullptr, 0, N_, WpZ, 8,
      gat_bias, ln2_g, ln2_b, nullptr, xb16, DD);

  // ---- RGCN layer 2 -> d_out (fp32), L2 normalize fused in epilogue ----
  k_makeW<<<576, 256, 0, stream>>>(r2_basis, r2_comp, r2_root, Wp);
  k_csr_agg<<<(N_ + 7) / 8, 256, 0, stream>>>(ptrb, epk, inv, xb16, agg16, N_);
  k_gemm_mfma<3><<<dim3(Mb, 1), 256, 0, stream>>>(agg16, LDA_AGG, 1024, xb16, 128, N_, Wp, 8,
      r2_bias, nullptr, nullptr, T2, nullptr, DD);
}

// Round 15
// 438.119 us; speedup vs baseline: 1.3404x; 1.3404x over previous
//
#include <hip/hip_runtime.h>
#include <hip/hip_bf16.h>

#define DD 128
#define NKEY8 8      // keys per dst = R
#define LDA_AGG 1056 // 1024 + 32 pad (non-pow2 row stride)
#define SRCM 0x00FFFFFF

using bf16x8 = __attribute__((ext_vector_type(8))) __bf16;
using f32x4  = __attribute__((ext_vector_type(4))) float;

__device__ __forceinline__ float leaky(float x, float s){ return x > 0.f ? x : s * x; }
__device__ __forceinline__ float bflo(unsigned u){ return __uint_as_float(u << 16); }
__device__ __forceinline__ float bfhi(unsigned u){ return __uint_as_float(u & 0xffff0000u); }
__device__ __forceinline__ unsigned bfpack(float x, float y){
  __hip_bfloat16 hx = __float2bfloat16(x), hy = __float2bfloat16(y);
  unsigned short ux = *reinterpret_cast<unsigned short*>(&hx);
  unsigned short uy = *reinterpret_cast<unsigned short*>(&hy);
  return (unsigned)ux | ((unsigned)uy << 16);
}

// ---------------- CSR build (counting sort by key = dst*8 + etype) ----------------
__global__ void k_hist(const int* __restrict__ dst, const int* __restrict__ et,
                       int* __restrict__ cnt, int E_){
  int e = blockIdx.x * 256 + threadIdx.x;
  if (e < E_) atomicAdd(&cnt[dst[e] * NKEY8 + et[e]], 1);
}

__global__ void k_scan1(const int* __restrict__ cnt, int* __restrict__ ptr,
                        int* __restrict__ part, int n){
  __shared__ int sm[256];
  int tid = threadIdx.x;
  int base = blockIdx.x * 1024 + tid * 4;
  int a0 = base + 0 < n ? cnt[base + 0] : 0;
  int a1 = base + 1 < n ? cnt[base + 1] : 0;
  int a2 = base + 2 < n ? cnt[base + 2] : 0;
  int a3 = base + 3 < n ? cnt[base + 3] : 0;
  int s = a0 + a1 + a2 + a3;
  sm[tid] = s; __syncthreads();
  for (int off = 1; off < 256; off <<= 1){
    int v = tid >= off ? sm[tid - off] : 0;
    __syncthreads(); sm[tid] += v; __syncthreads();
  }
  int ex = sm[tid] - s;
  if (tid == 255) part[blockIdx.x] = sm[255];
  if (base + 0 < n) ptr[base + 0] = ex;
  if (base + 1 < n) ptr[base + 1] = ex + a0;
  if (base + 2 < n) ptr[base + 2] = ex + a0 + a1;
  if (base + 3 < n) ptr[base + 3] = ex + a0 + a1 + a2;
}

__global__ void k_scan2(int* __restrict__ part, int nb){  // single block, 512 thr
  __shared__ int sm[512];
  int tid = threadIdx.x;
  int v = tid < nb ? part[tid] : 0;
  sm[tid] = v; __syncthreads();
  for (int off = 1; off < 512; off <<= 1){
    int u = tid >= off ? sm[tid - off] : 0;
    __syncthreads(); sm[tid] += u; __syncthreads();
  }
  if (tid < nb) part[tid] = sm[tid] - v;  // exclusive
}

__global__ void k_scan3(int* __restrict__ ptr, const int* __restrict__ part, int n, int E_){
  int i = blockIdx.x * 256 + threadIdx.x;
  if (i < n) ptr[i] += part[i >> 10];
  if (i == n) ptr[n] = E_;
}

// inv + init run (= ptr) in one pass
__global__ void k_inv(const int* __restrict__ ptr, float* __restrict__ inv,
                      int* __restrict__ run, int n){
  int i = blockIdx.x * 256 + threadIdx.x;
  if (i < n){
    int p = ptr[i];
    inv[i] = 1.0f / fmaxf((float)(ptr[i + 1] - p), 1.0f);
    run[i] = p;
  }
}

// epk[pos] = (etype << 24) | src   (sorted by (dst, etype))
__global__ void k_scatter_pos(const int* __restrict__ src, const int* __restrict__ dst,
                              const int* __restrict__ et, int* __restrict__ run,
                              int* __restrict__ epk, int E_){
  int e = blockIdx.x * 256 + threadIdx.x;
  if (e >= E_) return;
  int r = et[e];
  int pos = atomicAdd(&run[dst[e] * NKEY8 + r], 1);
  epk[pos] = (r << 24) | src[e];
}

__global__ void k_cvt(const float* __restrict__ in, __hip_bfloat16* __restrict__ out, int n){
  int i = blockIdx.x * 256 + threadIdx.x;
  if (i < n) out[i] = __float2bfloat16(in[i]);
}

// ---------------- weights: combine + pack into MFMA B-fragment order ----------------
__global__ void k_makeW(const float* __restrict__ basis, const float* __restrict__ comp,
                        const float* __restrict__ root, __hip_bfloat16* __restrict__ Wp){
  int idx = blockIdx.x * 256 + threadIdx.x;   // k*128 + n, k in [0,1152)
  int k = idx >> 7, n = idx & 127;
  float v;
  if (k < 1024){
    int r = k >> 7, i = k & 127;
    float s = 0.f;
    #pragma unroll
    for (int b = 0; b < 8; b++) s += comp[r * 8 + b] * basis[b * 16384 + i * 128 + n];
    v = s;
  } else {
    v = root[(k - 1024) * 128 + n];
  }
  int kt = k >> 5, kr = k & 31;
  int lane = (n & 15) | ((kr >> 3) << 4);
  int ii = kr & 7, nt = n >> 4;
  Wp[((size_t)(kt * 8 + nt) * 64 + lane) * 8 + ii] = __float2bfloat16(v);
}

// Wstack[h*128+i][n] = Wg[i][h*128+n], packed (ntt=8)
__global__ void k_packGZ(const float* __restrict__ Wg, __hip_bfloat16* __restrict__ Wp){
  int idx = blockIdx.x * 256 + threadIdx.x;   // k*128 + n, k in [0,512)
  int k = idx >> 7, n = idx & 127;
  int h = k >> 7, i = k & 127;
  float v = Wg[(size_t)i * 512 + h * 128 + n];
  int kt = k >> 5, kr = k & 31;
  int lane = (n & 15) | ((kr >> 3) << 4);
  int ii = kr & 7, nt = n >> 4;
  Wp[((size_t)(kt * 8 + nt) * 64 + lane) * 8 + ii] = __float2bfloat16(v);
}

// vT[sd][h][i] = sum_o Wg[i, h*128+o] * a_{src/dst}[h,o]
__global__ void k_valpha(const float* __restrict__ Wg, const float* __restrict__ a_src,
                         const float* __restrict__ a_dst, float* __restrict__ vT){
  int id = blockIdx.x * 256 + threadIdx.x;   // [0,1024)
  int sd = id >> 9, h = (id >> 7) & 3, i = id & 127;
  const float* a = (sd ? a_dst : a_src) + h * 128;
  const float* w = Wg + (size_t)i * 512 + h * 128;
  float s = 0.f;
  #pragma unroll 4
  for (int o = 0; o < 128; o++) s += w[o] * a[o];
  vT[(size_t)sd * 512 + h * 128 + i] = s;
}

// aS/aD from x directly: wave per node, 16 lanes per head
__global__ void k_av(const __hip_bfloat16* __restrict__ xb, const float* __restrict__ vT,
                     float* __restrict__ aS, float* __restrict__ aD, int N_){
  int node = blockIdx.x * 4 + (threadIdx.x >> 6);
  if (node >= N_) return;
  int lane = threadIdx.x & 63;
  int h = lane >> 4, dg = lane & 15;
  uint4 u = *(const uint4*)(xb + (size_t)node * DD + dg * 8);
  const float* vs = vT + h * 128 + dg * 8;
  const float* vd = vT + 512 + h * 128 + dg * 8;
  float ss = 0.f, sd = 0.f;
  #pragma unroll
  for (int w = 0; w < 4; w++){
    unsigned uw = ((const unsigned*)&u)[w];
    float f0 = bflo(uw), f1 = bfhi(uw);
    ss += f0 * vs[w * 2] + f1 * vs[w * 2 + 1];
    sd += f0 * vd[w * 2] + f1 * vd[w * 2 + 1];
  }
  for (int o = 1; o < 16; o <<= 1){ ss += __shfl_xor(ss, o); sd += __shfl_xor(sd, o); }
  if (dg == 0){ aS[(size_t)node * 4 + h] = ss; aD[(size_t)node * 4 + h] = sd; }
}

// ---------------- RGCN: CSR aggregation, half-wave-per-dst, 8-deep batch ----------------
__global__ void k_csr_agg(const int* __restrict__ ptr, const int* __restrict__ epk,
                          const float* __restrict__ inv, const __hip_bfloat16* __restrict__ xb,
                          __hip_bfloat16* __restrict__ agg, int N_){
  int w = threadIdx.x >> 6, lane = threadIdx.x & 63;
  int hw = lane >> 5, sl = lane & 31;
  int t = blockIdx.x * 8 + w * 2 + hw;
  if (t >= N_) return;
  int beg = ptr[t * 8], end = ptr[t * 8 + 8];
  const __hip_bfloat16* xcol = xb + sl * 4;
  __hip_bfloat16* aggrow = agg + (size_t)t * LDA_AGG + sl * 4;
  const float* invrow = inv + (size_t)t * 8;
  float a0 = 0.f, a1 = 0.f, a2 = 0.f, a3 = 0.f;
  int cur = -1;
  unsigned written = 0;

#define CSR_FLUSH() { float iv = invrow[cur]; \
    uint2 o_; o_.x = bfpack(a0 * iv, a1 * iv); o_.y = bfpack(a2 * iv, a3 * iv); \
    *(uint2*)(aggrow + cur * 128) = o_; written |= (1u << cur); }
#define CSR_PROC(PK, U) { int r_ = (PK) >> 24; \
    if (r_ != cur){ if (cur >= 0){ CSR_FLUSH(); } cur = r_; a0 = a1 = a2 = a3 = 0.f; } \
    a0 += bflo((U).x); a1 += bfhi((U).x); a2 += bflo((U).y); a3 += bfhi((U).y); }

  int e = beg;
  for (; e + 8 <= end; e += 8){
    int pk0 = epk[e],     pk1 = epk[e + 1], pk2 = epk[e + 2], pk3 = epk[e + 3];
    int pk4 = epk[e + 4], pk5 = epk[e + 5], pk6 = epk[e + 6], pk7 = epk[e + 7];
    uint2 u0 = *(const uint2*)(xcol + (size_t)(pk0 & SRCM) * DD);
    uint2 u1 = *(const uint2*)(xcol + (size_t)(pk1 & SRCM) * DD);
    uint2 u2 = *(const uint2*)(xcol + (size_t)(pk2 & SRCM) * DD);
    uint2 u3 = *(const uint2*)(xcol + (size_t)(pk3 & SRCM) * DD);
    uint2 u4 = *(const uint2*)(xcol + (size_t)(pk4 & SRCM) * DD);
    uint2 u5 = *(const uint2*)(xcol + (size_t)(pk5 & SRCM) * DD);
    uint2 u6 = *(const uint2*)(xcol + (size_t)(pk6 & SRCM) * DD);
    uint2 u7 = *(const uint2*)(xcol + (size_t)(pk7 & SRCM) * DD);
    CSR_PROC(pk0, u0); CSR_PROC(pk1, u1); CSR_PROC(pk2, u2); CSR_PROC(pk3, u3);
    CSR_PROC(pk4, u4); CSR_PROC(pk5, u5); CSR_PROC(pk6, u6); CSR_PROC(pk7, u7);
  }
  for (; e + 4 <= end; e += 4){
    int pk0 = epk[e], pk1 = epk[e + 1], pk2 = epk[e + 2], pk3 = epk[e + 3];
    uint2 u0 = *(const uint2*)(xcol + (size_t)(pk0 & SRCM) * DD);
    uint2 u1 = *(const uint2*)(xcol + (size_t)(pk1 & SRCM) * DD);
    uint2 u2 = *(const uint2*)(xcol + (size_t)(pk2 & SRCM) * DD);
    uint2 u3 = *(const uint2*)(xcol + (size_t)(pk3 & SRCM) * DD);
    CSR_PROC(pk0, u0); CSR_PROC(pk1, u1); CSR_PROC(pk2, u2); CSR_PROC(pk3, u3);
  }
  for (; e < end; e++){
    int pk0 = epk[e];
    uint2 u0 = *(const uint2*)(xcol + (size_t)(pk0 & SRCM) * DD);
    CSR_PROC(pk0, u0);
  }
  if (cur >= 0){ CSR_FLUSH(); }
  uint2 z_; z_.x = 0u; z_.y = 0u;
  #pragma unroll
  for (int r = 0; r < 8; r++)
    if (!(written & (1u << r))) *(uint2*)(aggrow + r * 128) = z_;
#undef CSR_PROC
#undef CSR_FLUSH
}

// ---------------- GAT: coef-weighted aggregation of x into z[N,512], 4-deep ----------------
__global__ void k_zagg(const int* __restrict__ ptr, const int* __restrict__ epk,
                       const float* __restrict__ cf, const float* __restrict__ cfS,
                       const float* __restrict__ den, const __hip_bfloat16* __restrict__ xb,
                       __hip_bfloat16* __restrict__ z, int N_){
  int w = threadIdx.x >> 6, lane = threadIdx.x & 63;
  int t = blockIdx.x * 4 + w;
  if (t >= N_) return;
  int dg = lane & 31, ep = lane >> 5;
  int beg = ptr[t * 8], end = ptr[t * 8 + 8];
  float acc[4][4];
  #pragma unroll
  for (int h = 0; h < 4; h++)
    #pragma unroll
    for (int j = 0; j < 4; j++) acc[h][j] = 0.f;
  const __hip_bfloat16* xbase = xb + dg * 4;

#define ZPROC(V, C) { \
    float f0 = bflo((V).x), f1 = bfhi((V).x), f2 = bflo((V).y), f3 = bfhi((V).y); \
    const float* cp = (const float*)&(C); \
    _Pragma("unroll") \
    for (int h = 0; h < 4; h++){ \
      acc[h][0] += cp[h] * f0; acc[h][1] += cp[h] * f1; \
      acc[h][2] += cp[h] * f2; acc[h][3] += cp[h] * f3; } }

  int e = beg + ep;
  for (; e + 6 < end; e += 8){
    int s0 = epk[e] & SRCM,     s1 = epk[e + 2] & SRCM;
    int s2 = epk[e + 4] & SRCM, s3 = epk[e + 6] & SRCM;
    uint2 v0 = *(const uint2*)(xbase + (size_t)s0 * DD);
    uint2 v1 = *(const uint2*)(xbase + (size_t)s1 * DD);
    uint2 v2 = *(const uint2*)(xbase + (size_t)s2 * DD);
    uint2 v3 = *(const uint2*)(xbase + (size_t)s3 * DD);
    float4 c0 = *(const float4*)(cf + (size_t)e * 4);
    float4 c1 = *(const float4*)(cf + (size_t)(e + 2) * 4);
    float4 c2 = *(const float4*)(cf + (size_t)(e + 4) * 4);
    float4 c3 = *(const float4*)(cf + (size_t)(e + 6) * 4);
    ZPROC(v0, c0); ZPROC(v1, c1); ZPROC(v2, c2); ZPROC(v3, c3);
  }
  for (; e < end; e += 2){
    int s = epk[e] & SRCM;
    uint2 v = *(const uint2*)(xbase + (size_t)s * DD);
    float4 c = *(const float4*)(cf + (size_t)e * 4);
    ZPROC(v, c);
  }
#undef ZPROC
  #pragma unroll
  for (int h = 0; h < 4; h++)
    #pragma unroll
    for (int j = 0; j < 4; j++) acc[h][j] += __shfl_xor(acc[h][j], 32);
  if (ep == 0){
    uint2 v = *(const uint2*)(xbase + (size_t)t * DD);
    float f0 = bflo(v.x), f1 = bfhi(v.x), f2 = bflo(v.y), f3 = bfhi(v.y);
    float4 cs = *(const float4*)(cfS + (size_t)t * 4);
    float4 dn = *(const float4*)(den + (size_t)t * 4);
    const float* csp = (const float*)&cs;
    const float* dnp = (const float*)&dn;
    #pragma unroll
    for (int h = 0; h < 4; h++){
      float sc = 0.25f / dnp[h];
      float y0 = (acc[h][0] + csp[h] * f0) * sc;
      float y1 = (acc[h][1] + csp[h] * f1) * sc;
      float y2 = (acc[h][2] + csp[h] * f2) * sc;
      float y3 = (acc[h][3] + csp[h] * f3) * sc;
      uint2 o; o.x = bfpack(y0, y1); o.y = bfpack(y2, y3);
      *(uint2*)(z + (size_t)t * 512 + h * 128 + dg * 4) = o;
    }
  }
}

// ---------------- MFMA GEMM, 128-row tiles, split-A, fused epilogues (round-12 shape) ------
// MODE 1: Cb = leaky(LN(acc+bias)).  MODE 3: Cf = L2normalize(acc+bias).
template<int MODE>
__launch_bounds__(256)
__global__ void k_gemm_mfma(const __hip_bfloat16* __restrict__ A1, int lda1, int K1,
                            const __hip_bfloat16* __restrict__ A2, int K2,
                            int M, const __hip_bfloat16* __restrict__ Bp, int ntt,
                            const float* __restrict__ bias,
                            const float* __restrict__ ln_g, const float* __restrict__ ln_b,
                            float* __restrict__ Cf, __hip_bfloat16* __restrict__ Cb,
                            int ldc){
  int wave = threadIdx.x >> 6, lane = threadIdx.x & 63;
  int nt0 = blockIdx.y << 3;
  int mbase = blockIdx.x * 128 + wave * 32;
  int r0 = min(mbase + (lane & 15), M - 1);
  int r1 = min(mbase + 16 + (lane & 15), M - 1);
  int koff = (lane >> 4) << 3;
  f32x4 acc[2][8];
  #pragma unroll
  for (int i = 0; i < 2; i++)
    #pragma unroll
    for (int j = 0; j < 8; j++) acc[i][j] = (f32x4){0.f, 0.f, 0.f, 0.f};

  int ktile = 0;
  {
    const __hip_bfloat16* a0p = A1 + (size_t)r0 * lda1 + koff;
    const __hip_bfloat16* a1p = A1 + (size_t)r1 * lda1 + koff;
    for (int k0 = 0; k0 < K1; k0 += 32, ++ktile){
      bf16x8 a0 = *(const bf16x8*)(a0p + k0);
      bf16x8 a1 = *(const bf16x8*)(a1p + k0);
      const bf16x8* bfr = (const bf16x8*)(Bp + (((size_t)ktile * ntt + nt0) * 64 + lane) * 8);
      #pragma unroll
      for (int nt = 0; nt < 8; nt++){
        bf16x8 b = bfr[(size_t)nt * 64];
        acc[0][nt] = __builtin_amdgcn_mfma_f32_16x16x32_bf16(a0, b, acc[0][nt], 0, 0, 0);
        acc[1][nt] = __builtin_amdgcn_mfma_f32_16x16x32_bf16(a1, b, acc[1][nt], 0, 0, 0);
      }
    }
  }
  if (A2){
    const __hip_bfloat16* a0p = A2 + (size_t)r0 * DD + koff;
    const __hip_bfloat16* a1p = A2 + (size_t)r1 * DD + koff;
    for (int k0 = 0; k0 < K2; k0 += 32, ++ktile){
      bf16x8 a0 = *(const bf16x8*)(a0p + k0);
      bf16x8 a1 = *(const bf16x8*)(a1p + k0);
      const bf16x8* bfr = (const bf16x8*)(Bp + (((size_t)ktile * ntt + nt0) * 64 + lane) * 8);
      #pragma unroll
      for (int nt = 0; nt < 8; nt++){
        bf16x8 b = bfr[(size_t)nt * 64];
        acc[0][nt] = __builtin_amdgcn_mfma_f32_16x16x32_bf16(a0, b, acc[0][nt], 0, 0, 0);
        acc[1][nt] = __builtin_amdgcn_mfma_f32_16x16x32_bf16(a1, b, acc[1][nt], 0, 0, 0);
      }
    }
  }

  const int colb = lane & 15;
  const int lq = lane >> 4;

  float bias8[8], g8[8], b8[8];
  #pragma unroll
  for (int nt = 0; nt < 8; nt++){
    int c = (nt << 4) + colb;
    bias8[nt] = bias ? bias[c] : 0.f;
    if (MODE == 1){ g8[nt] = ln_g[c]; b8[nt] = ln_b[c]; }
  }

  #pragma unroll
  for (int mt = 0; mt < 2; mt++){
    #pragma unroll
    for (int j = 0; j < 4; j++){
      int row = mbase + mt * 16 + lq * 4 + j;
      if (MODE == 1){
        float v[8]; float s = 0.f;
        #pragma unroll
        for (int nt = 0; nt < 8; nt++){ v[nt] = acc[mt][nt][j] + bias8[nt]; s += v[nt]; }
        #pragma unroll
        for (int o = 1; o < 16; o <<= 1) s += __shfl_xor(s, o);
        float mu = s * (1.f / 128.f);
        float q = 0.f;
        #pragma unroll
        for (int nt = 0; nt < 8; nt++){ float dd = v[nt] - mu; q += dd * dd; }
        #pragma unroll
        for (int o = 1; o < 16; o <<= 1) q += __shfl_xor(q, o);
        float rstd = rsqrtf(q * (1.f / 128.f) + 1e-5f);
        if (row < M){
          #pragma unroll
          for (int nt = 0; nt < 8; nt++){
            float y = leaky((v[nt] - mu) * rstd * g8[nt] + b8[nt], 0.1f);
            Cb[(size_t)row * ldc + (nt << 4) + colb] = __float2bfloat16(y);
          }
        }
      } else { // MODE 3: bias + L2 normalize, fp32 out
        float v[8]; float q = 0.f;
        #pragma unroll
        for (int nt = 0; nt < 8; nt++){ v[nt] = acc[mt][nt][j] + bias8[nt]; q += v[nt] * v[nt]; }
        #pragma unroll
        for (int o = 1; o < 16; o <<= 1) q += __shfl_xor(q, o);
        float sc = 1.0f / fmaxf(sqrtf(q), 1e-12f);
        if (row < M){
          #pragma unroll
          for (int nt = 0; nt < 8; nt++)
            Cf[(size_t)row * ldc + (nt << 4) + colb] = v[nt] * sc;
        }
      }
    }
  }
}

// ---------------- GAT: per-(dst,head) softmax coefficients ----------------
// Pass 1 gathers aS once and stores LOGITS into cf; pass 2 streams cf (sequential).
__global__ void k_gat_coef(const int* __restrict__ ptr, const int* __restrict__ epk,
                           const float* __restrict__ aS, const float* __restrict__ aD,
                           float* __restrict__ cf, float* __restrict__ cfS,
                           float* __restrict__ den, int N_){
  int id = blockIdx.x * 256 + threadIdx.x;
  int t = id >> 2, h = id & 3;
  if (t >= N_) return;
  int beg = ptr[t * 8], end = ptr[t * 8 + 8];
  float adh = aD[(size_t)t * 4 + h];
  float ash = aS[(size_t)t * 4 + h];
  float selfe = leaky(ash + adh, 0.2f);
  float m = selfe;
  for (int e = beg; e < end; e++){
    int s = epk[e] & SRCM;
    float l = leaky(aS[(size_t)s * 4 + h] + adh, 0.2f);
    cf[(size_t)e * 4 + h] = l;
    m = fmaxf(m, l);
  }
  float sv = __expf(selfe - m);
  cfS[(size_t)t * 4 + h] = sv;
  float d = sv;
  for (int e = beg; e < end; e++){
    float x = __expf(cf[(size_t)e * 4 + h] - m);
    cf[(size_t)e * 4 + h] = x;
    d += x;
  }
  den[(size_t)t * 4 + h] = d;
}

extern "C" void kernel_launch(void* const* d_in, const int* in_sizes, int n_in,
                              void* d_out, int out_size, void* d_ws, size_t ws_size,
                              hipStream_t stream){
  const float* x       = (const float*)d_in[0];
  const int*   ei      = (const int*)d_in[1];
  const int*   et      = (const int*)d_in[2];
  const float* r0_basis= (const float*)d_in[3];  const float* r0_comp = (const float*)d_in[4];
  const float* r0_root = (const float*)d_in[5];  const float* r0_bias = (const float*)d_in[6];
  const float* ln0_g   = (const float*)d_in[7];  const float* ln0_b   = (const float*)d_in[8];
  const float* r1_basis= (const float*)d_in[9];  const float* r1_comp = (const float*)d_in[10];
  const float* r1_root = (const float*)d_in[11]; const float* r1_bias = (const float*)d_in[12];
  const float* ln1_g   = (const float*)d_in[13]; const float* ln1_b   = (const float*)d_in[14];
  const float* gat_w   = (const float*)d_in[15]; const float* gat_asrc= (const float*)d_in[16];
  const float* gat_adst= (const float*)d_in[17]; const float* gat_bias= (const float*)d_in[18];
  const float* ln2_g   = (const float*)d_in[19]; const float* ln2_b   = (const float*)d_in[20];
  const float* r2_basis= (const float*)d_in[21]; const float* r2_comp = (const float*)d_in[22];
  const float* r2_root = (const float*)d_in[23]; const float* r2_bias = (const float*)d_in[24];

  const int N_ = in_sizes[0] / DD;
  const int E_ = in_sizes[2];
  const int NK = N_ * NKEY8;
  const int* src = ei;
  const int* dst = ei + E_;
  float* T2 = (float*)d_out;

  char* wp_ = (char*)d_ws;
  auto alloc = [&](size_t b)->void*{ void* p = wp_; wp_ += (b + 255) & ~(size_t)255; return p; };
  __hip_bfloat16* agg16 = (__hip_bfloat16*)alloc((size_t)N_ * LDA_AGG * 2);  // also hosts z16
  __hip_bfloat16* xb16  = (__hip_bfloat16*)alloc((size_t)N_ * DD * 2);
  float*          inv   = (float*)alloc((size_t)NK * 4);
  int*            ptrb  = (int*)alloc((size_t)(NK + 1) * 4);
  int*            cnt   = (int*)alloc((size_t)NK * 4);
  int*            run   = (int*)alloc((size_t)NK * 4);
  int*            epk   = (int*)alloc((size_t)E_ * 4);
  int*            part  = (int*)alloc(512 * 4);
  float*          aS    = (float*)alloc((size_t)N_ * 4 * 4);
  float*          aD    = (float*)alloc((size_t)N_ * 4 * 4);
  float*          cf    = (float*)alloc((size_t)E_ * 4 * 4);
  float*          cfS   = (float*)alloc((size_t)N_ * 4 * 4);
  float*          den   = (float*)alloc((size_t)N_ * 4 * 4);
  float*          vT    = (float*)alloc((size_t)2 * 512 * 4);
  __hip_bfloat16* Wp    = (__hip_bfloat16*)alloc((size_t)1152 * 128 * 2);
  __hip_bfloat16* WpZ   = (__hip_bfloat16*)alloc((size_t)512 * 128 * 2);
  if ((size_t)(wp_ - (char*)d_ws) > ws_size) return;
  __hip_bfloat16* z16 = agg16;   // aliased: agg dead when z is live, and vice versa

  const int Mb = (N_ + 127) / 128;
  const int nScanB = (NK + 1023) / 1024;

  // ---- CSR build (same graph for all layers) ----
  hipMemsetAsync(cnt, 0, (size_t)NK * 4, stream);
  k_hist<<<(E_ + 255) / 256, 256, 0, stream>>>(dst, et, cnt, E_);
  k_scan1<<<nScanB, 256, 0, stream>>>(cnt, ptrb, part, NK);
  k_scan2<<<1, 512, 0, stream>>>(part, nScanB);
  k_scan3<<<(NK + 1 + 255) / 256, 256, 0, stream>>>(ptrb, part, NK, E_);
  k_inv<<<(NK + 255) / 256, 256, 0, stream>>>(ptrb, inv, run, NK);
  k_scatter_pos<<<(E_ + 255) / 256, 256, 0, stream>>>(src, dst, et, run, epk, E_);
  k_cvt<<<(N_ * DD + 255) / 256, 256, 0, stream>>>(x, xb16, N_ * DD);

  // ---- RGCN layer 0 (LN0+leaky fused) ----
  k_makeW<<<576, 256, 0, stream>>>(r0_basis, r0_comp, r0_root, Wp);
  k_csr_agg<<<(N_ + 7) / 8, 256, 0, stream>>>(ptrb, epk, inv, xb16, agg16, N_);
  k_gemm_mfma<1><<<dim3(Mb, 1), 256, 0, stream>>>(agg16, LDA_AGG, 1024, xb16, 128, N_, Wp, 8,
      r0_bias, ln0_g, ln0_b, nullptr, xb16, DD);

  // ---- RGCN layer 1 (LN1+leaky fused) ----
  k_makeW<<<576, 256, 0, stream>>>(r1_basis, r1_comp, r1_root, Wp);
  k_csr_agg<<<(N_ + 7) / 8, 256, 0, stream>>>(ptrb, epk, inv, xb16, agg16, N_);
  k_gemm_mfma<1><<<dim3(Mb, 1), 256, 0, stream>>>(agg16, LDA_AGG, 1024, xb16, 128, N_, Wp, 8,
      r1_bias, ln1_g, ln1_b, nullptr, xb16, DD);

  // ---- GAT: logits from x (no hH), coef, z-aggregate, K=512 GEMM (+bias+LN2 fused) ----
  k_valpha<<<4, 256, 0, stream>>>(gat_w, gat_asrc, gat_adst, vT);
  k_packGZ<<<256, 256, 0, stream>>>(gat_w, WpZ);
  k_av<<<(N_ + 3) / 4, 256, 0, stream>>>(xb16, vT, aS, aD, N_);
  k_gat_coef<<<(N_ * 4 + 255) / 256, 256, 0, stream>>>(ptrb, epk, aS, aD, cf, cfS, den, N_);
  k_zagg<<<(N_ + 3) / 4, 256, 0, stream>>>(ptrb, epk, cf, cfS, den, xb16, z16, N_);
  k_gemm_mfma<1><<<dim3(Mb, 1), 256, 0, stream>>>(z16, 512, 512, nullptr, 0, N_, WpZ, 8,
      gat_bias, ln2_g, ln2_b, nullptr, xb16, DD);

  // ---- RGCN layer 2 -> d_out (fp32), L2 normalize fused in epilogue ----
  k_makeW<<<576, 256, 0, stream>>>(r2_basis, r2_comp, r2_root, Wp);
  k_csr_agg<<<(N_ + 7) / 8, 256, 0, stream>>>(ptrb, epk, inv, xb16, agg16, N_);
  k_gemm_mfma<3><<<dim3(Mb, 1), 256, 0, stream>>>(agg16, LDA_AGG, 1024, xb16, 128, N_, Wp, 8,
      r2_bias, nullptr, nullptr, T2, nullptr, DD);
}

// Round 16
// 426.558 us; speedup vs baseline: 1.3767x; 1.0271x over previous
//
#include <hip/hip_runtime.h>
#include <hip/hip_bf16.h>

#define DD 128
#define NKEY8 8      // keys per dst = R
#define LDA_AGG 1056 // 1024 + 32 pad (non-pow2 row stride)
#define SRCM 0x00FFFFFF

using bf16x8 = __attribute__((ext_vector_type(8))) __bf16;
using f32x4  = __attribute__((ext_vector_type(4))) float;

__device__ __forceinline__ float leaky(float x, float s){ return x > 0.f ? x : s * x; }
__device__ __forceinline__ float bflo(unsigned u){ return __uint_as_float(u << 16); }
__device__ __forceinline__ float bfhi(unsigned u){ return __uint_as_float(u & 0xffff0000u); }
__device__ __forceinline__ unsigned bfpack(float x, float y){
  __hip_bfloat16 hx = __float2bfloat16(x), hy = __float2bfloat16(y);
  unsigned short ux = *reinterpret_cast<unsigned short*>(&hx);
  unsigned short uy = *reinterpret_cast<unsigned short*>(&hy);
  return (unsigned)ux | ((unsigned)uy << 16);
}

// ---------------- CSR build (counting sort by key = dst*8 + etype) ----------------
// hist + x->bf16 cvt in one launch (independent work, block-range dispatch)
__global__ void k_hist_cvt(const int* __restrict__ dst, const int* __restrict__ et,
                           int* __restrict__ cnt, int E_, int histB,
                           const float* __restrict__ x, __hip_bfloat16* __restrict__ xb, int nx){
  if ((int)blockIdx.x < histB){
    int e = blockIdx.x * 256 + threadIdx.x;
    if (e < E_) atomicAdd(&cnt[dst[e] * NKEY8 + et[e]], 1);
  } else {
    int i = (blockIdx.x - histB) * 256 + threadIdx.x;
    if (i < nx) xb[i] = __float2bfloat16(x[i]);
  }
}

__global__ void k_scan1(const int* __restrict__ cnt, int* __restrict__ praw,
                        int* __restrict__ part, int n){
  __shared__ int sm[256];
  int tid = threadIdx.x;
  int base = blockIdx.x * 1024 + tid * 4;
  int a0 = base + 0 < n ? cnt[base + 0] : 0;
  int a1 = base + 1 < n ? cnt[base + 1] : 0;
  int a2 = base + 2 < n ? cnt[base + 2] : 0;
  int a3 = base + 3 < n ? cnt[base + 3] : 0;
  int s = a0 + a1 + a2 + a3;
  sm[tid] = s; __syncthreads();
  for (int off = 1; off < 256; off <<= 1){
    int v = tid >= off ? sm[tid - off] : 0;
    __syncthreads(); sm[tid] += v; __syncthreads();
  }
  int ex = sm[tid] - s;
  if (tid == 255) part[blockIdx.x] = sm[255];
  if (base + 0 < n) praw[base + 0] = ex;
  if (base + 1 < n) praw[base + 1] = ex + a0;
  if (base + 2 < n) praw[base + 2] = ex + a0 + a1;
  if (base + 3 < n) praw[base + 3] = ex + a0 + a1 + a2;
}

__global__ void k_scan2(int* __restrict__ part, int nb){  // single block, 512 thr
  __shared__ int sm[512];
  int tid = threadIdx.x;
  int v = tid < nb ? part[tid] : 0;
  sm[tid] = v; __syncthreads();
  for (int off = 1; off < 512; off <<= 1){
    int u = tid >= off ? sm[tid - off] : 0;
    __syncthreads(); sm[tid] += u; __syncthreads();
  }
  if (tid < nb) part[tid] = sm[tid] - v;  // exclusive
}

// final ptr + inv + run in one pass (reads raw scan, no in-place hazard)
__global__ void k_scan3i(const int* __restrict__ praw, const int* __restrict__ part,
                         int* __restrict__ ptrb, float* __restrict__ inv,
                         int* __restrict__ run, int n, int E_){
  int i = blockIdx.x * 256 + threadIdx.x;
  if (i >= n) return;
  int fi   = praw[i] + part[i >> 10];
  int fip1 = (i + 1 < n) ? (praw[i + 1] + part[(i + 1) >> 10]) : E_;
  ptrb[i] = fi;
  inv[i]  = 1.0f / fmaxf((float)(fip1 - fi), 1.0f);
  run[i]  = fi;
  if (i == n - 1) ptrb[n] = E_;
}

// epk[pos] = (etype << 24) | src   (sorted by (dst, etype))
__global__ void k_scatter_pos(const int* __restrict__ src, const int* __restrict__ dst,
                              const int* __restrict__ et, int* __restrict__ run,
                              int* __restrict__ epk, int E_){
  int e = blockIdx.x * 256 + threadIdx.x;
  if (e >= E_) return;
  int r = et[e];
  int pos = atomicAdd(&run[dst[e] * NKEY8 + r], 1);
  epk[pos] = (r << 24) | src[e];
}

// ---------------- all weight prep in ONE launch ----------------
// blocks [0,1728): makeW for layers 0/1/2 (576 each)
// blocks [1728,1984): packGZ; blocks [1984,1988): valpha
__global__ void k_prep(const float* __restrict__ b0, const float* __restrict__ c0,
                       const float* __restrict__ r0,
                       const float* __restrict__ b1, const float* __restrict__ c1,
                       const float* __restrict__ r1,
                       const float* __restrict__ b2, const float* __restrict__ c2,
                       const float* __restrict__ r2,
                       const float* __restrict__ Wg, const float* __restrict__ a_src,
                       const float* __restrict__ a_dst,
                       __hip_bfloat16* __restrict__ Wp0, __hip_bfloat16* __restrict__ Wp1,
                       __hip_bfloat16* __restrict__ Wp2, __hip_bfloat16* __restrict__ WpZ,
                       float* __restrict__ vT){
  int blk = blockIdx.x;
  if (blk < 1728){
    int layer = blk / 576;
    int idx = (blk % 576) * 256 + threadIdx.x;   // k*128 + n, k in [0,1152)
    const float* basis = layer == 0 ? b0 : layer == 1 ? b1 : b2;
    const float* comp  = layer == 0 ? c0 : layer == 1 ? c1 : c2;
    const float* root  = layer == 0 ? r0 : layer == 1 ? r1 : r2;
    __hip_bfloat16* Wp = layer == 0 ? Wp0 : layer == 1 ? Wp1 : Wp2;
    int k = idx >> 7, n = idx & 127;
    float v;
    if (k < 1024){
      int r = k >> 7, i = k & 127;
      float s = 0.f;
      #pragma unroll
      for (int b = 0; b < 8; b++) s += comp[r * 8 + b] * basis[b * 16384 + i * 128 + n];
      v = s;
    } else {
      v = root[(k - 1024) * 128 + n];
    }
    int kt = k >> 5, kr = k & 31;
    int lane = (n & 15) | ((kr >> 3) << 4);
    int ii = kr & 7, nt = n >> 4;
    Wp[((size_t)(kt * 8 + nt) * 64 + lane) * 8 + ii] = __float2bfloat16(v);
  } else if (blk < 1984){
    int idx = (blk - 1728) * 256 + threadIdx.x;  // k*128 + n, k in [0,512)
    int k = idx >> 7, n = idx & 127;
    int h = k >> 7, i = k & 127;
    float v = Wg[(size_t)i * 512 + h * 128 + n];
    int kt = k >> 5, kr = k & 31;
    int lane = (n & 15) | ((kr >> 3) << 4);
    int ii = kr & 7, nt = n >> 4;
    WpZ[((size_t)(kt * 8 + nt) * 64 + lane) * 8 + ii] = __float2bfloat16(v);
  } else {
    int id = (blk - 1984) * 256 + threadIdx.x;   // [0,1024)
    int sd = id >> 9, h = (id >> 7) & 3, i = id & 127;
    const float* a = (sd ? a_dst : a_src) + h * 128;
    const float* w = Wg + (size_t)i * 512 + h * 128;
    float s = 0.f;
    #pragma unroll 4
    for (int o = 0; o < 128; o++) s += w[o] * a[o];
    vT[(size_t)sd * 512 + h * 128 + i] = s;
  }
}

// aS/aD from x directly: wave per node, 16 lanes per head
__global__ void k_av(const __hip_bfloat16* __restrict__ xb, const float* __restrict__ vT,
                     float* __restrict__ aS, float* __restrict__ aD, int N_){
  int node = blockIdx.x * 4 + (threadIdx.x >> 6);
  if (node >= N_) return;
  int lane = threadIdx.x & 63;
  int h = lane >> 4, dg = lane & 15;
  uint4 u = *(const uint4*)(xb + (size_t)node * DD + dg * 8);
  const float* vs = vT + h * 128 + dg * 8;
  const float* vd = vT + 512 + h * 128 + dg * 8;
  float ss = 0.f, sd = 0.f;
  #pragma unroll
  for (int w = 0; w < 4; w++){
    unsigned uw = ((const unsigned*)&u)[w];
    float f0 = bflo(uw), f1 = bfhi(uw);
    ss += f0 * vs[w * 2] + f1 * vs[w * 2 + 1];
    sd += f0 * vd[w * 2] + f1 * vd[w * 2 + 1];
  }
  for (int o = 1; o < 16; o <<= 1){ ss += __shfl_xor(ss, o); sd += __shfl_xor(sd, o); }
  if (dg == 0){ aS[(size_t)node * 4 + h] = ss; aD[(size_t)node * 4 + h] = sd; }
}

// ---------------- RGCN: CSR aggregation, half-wave-per-dst, 8-deep batch ----------------
__global__ void k_csr_agg(const int* __restrict__ ptr, const int* __restrict__ epk,
                          const float* __restrict__ inv, const __hip_bfloat16* __restrict__ xb,
                          __hip_bfloat16* __restrict__ agg, int N_){
  int w = threadIdx.x >> 6, lane = threadIdx.x & 63;
  int hw = lane >> 5, sl = lane & 31;
  int t = blockIdx.x * 8 + w * 2 + hw;
  if (t >= N_) return;
  int beg = ptr[t * 8], end = ptr[t * 8 + 8];
  const __hip_bfloat16* xcol = xb + sl * 4;
  __hip_bfloat16* aggrow = agg + (size_t)t * LDA_AGG + sl * 4;
  const float* invrow = inv + (size_t)t * 8;
  float a0 = 0.f, a1 = 0.f, a2 = 0.f, a3 = 0.f;
  int cur = -1;
  unsigned written = 0;

#define CSR_FLUSH() { float iv = invrow[cur]; \
    uint2 o_; o_.x = bfpack(a0 * iv, a1 * iv); o_.y = bfpack(a2 * iv, a3 * iv); \
    *(uint2*)(aggrow + cur * 128) = o_; written |= (1u << cur); }
#define CSR_PROC(PK, U) { int r_ = (PK) >> 24; \
    if (r_ != cur){ if (cur >= 0){ CSR_FLUSH(); } cur = r_; a0 = a1 = a2 = a3 = 0.f; } \
    a0 += bflo((U).x); a1 += bfhi((U).x); a2 += bflo((U).y); a3 += bfhi((U).y); }

  int e = beg;
  for (; e + 8 <= end; e += 8){
    int pk0 = epk[e],     pk1 = epk[e + 1], pk2 = epk[e + 2], pk3 = epk[e + 3];
    int pk4 = epk[e + 4], pk5 = epk[e + 5], pk6 = epk[e + 6], pk7 = epk[e + 7];
    uint2 u0 = *(const uint2*)(xcol + (size_t)(pk0 & SRCM) * DD);
    uint2 u1 = *(const uint2*)(xcol + (size_t)(pk1 & SRCM) * DD);
    uint2 u2 = *(const uint2*)(xcol + (size_t)(pk2 & SRCM) * DD);
    uint2 u3 = *(const uint2*)(xcol + (size_t)(pk3 & SRCM) * DD);
    uint2 u4 = *(const uint2*)(xcol + (size_t)(pk4 & SRCM) * DD);
    uint2 u5 = *(const uint2*)(xcol + (size_t)(pk5 & SRCM) * DD);
    uint2 u6 = *(const uint2*)(xcol + (size_t)(pk6 & SRCM) * DD);
    uint2 u7 = *(const uint2*)(xcol + (size_t)(pk7 & SRCM) * DD);
    CSR_PROC(pk0, u0); CSR_PROC(pk1, u1); CSR_PROC(pk2, u2); CSR_PROC(pk3, u3);
    CSR_PROC(pk4, u4); CSR_PROC(pk5, u5); CSR_PROC(pk6, u6); CSR_PROC(pk7, u7);
  }
  for (; e + 4 <= end; e += 4){
    int pk0 = epk[e], pk1 = epk[e + 1], pk2 = epk[e + 2], pk3 = epk[e + 3];
    uint2 u0 = *(const uint2*)(xcol + (size_t)(pk0 & SRCM) * DD);
    uint2 u1 = *(const uint2*)(xcol + (size_t)(pk1 & SRCM) * DD);
    uint2 u2 = *(const uint2*)(xcol + (size_t)(pk2 & SRCM) * DD);
    uint2 u3 = *(const uint2*)(xcol + (size_t)(pk3 & SRCM) * DD);
    CSR_PROC(pk0, u0); CSR_PROC(pk1, u1); CSR_PROC(pk2, u2); CSR_PROC(pk3, u3);
  }
  for (; e < end; e++){
    int pk0 = epk[e];
    uint2 u0 = *(const uint2*)(xcol + (size_t)(pk0 & SRCM) * DD);
    CSR_PROC(pk0, u0);
  }
  if (cur >= 0){ CSR_FLUSH(); }
  uint2 z_; z_.x = 0u; z_.y = 0u;
  #pragma unroll
  for (int r = 0; r < 8; r++)
    if (!(written & (1u << r))) *(uint2*)(aggrow + r * 128) = z_;
#undef CSR_PROC
#undef CSR_FLUSH
}

// ---------------- GAT: coef-weighted aggregation of x into z[N,512], 4-deep ----------------
__global__ void k_zagg(const int* __restrict__ ptr, const int* __restrict__ epk,
                       const float* __restrict__ cf, const float* __restrict__ cfS,
                       const float* __restrict__ den, const __hip_bfloat16* __restrict__ xb,
                       __hip_bfloat16* __restrict__ z, int N_){
  int w = threadIdx.x >> 6, lane = threadIdx.x & 63;
  int t = blockIdx.x * 4 + w;
  if (t >= N_) return;
  int dg = lane & 31, ep = lane >> 5;
  int beg = ptr[t * 8], end = ptr[t * 8 + 8];
  float acc[4][4];
  #pragma unroll
  for (int h = 0; h < 4; h++)
    #pragma unroll
    for (int j = 0; j < 4; j++) acc[h][j] = 0.f;
  const __hip_bfloat16* xbase = xb + dg * 4;

#define ZPROC(V, C) { \
    float f0 = bflo((V).x), f1 = bfhi((V).x), f2 = bflo((V).y), f3 = bfhi((V).y); \
    const float* cp = (const float*)&(C); \
    _Pragma("unroll") \
    for (int h = 0; h < 4; h++){ \
      acc[h][0] += cp[h] * f0; acc[h][1] += cp[h] * f1; \
      acc[h][2] += cp[h] * f2; acc[h][3] += cp[h] * f3; } }

  int e = beg + ep;
  for (; e + 6 < end; e += 8){
    int s0 = epk[e] & SRCM,     s1 = epk[e + 2] & SRCM;
    int s2 = epk[e + 4] & SRCM, s3 = epk[e + 6] & SRCM;
    uint2 v0 = *(const uint2*)(xbase + (size_t)s0 * DD);
    uint2 v1 = *(const uint2*)(xbase + (size_t)s1 * DD);
    uint2 v2 = *(const uint2*)(xbase + (size_t)s2 * DD);
    uint2 v3 = *(const uint2*)(xbase + (size_t)s3 * DD);
    float4 c0 = *(const float4*)(cf + (size_t)e * 4);
    float4 c1 = *(const float4*)(cf + (size_t)(e + 2) * 4);
    float4 c2 = *(const float4*)(cf + (size_t)(e + 4) * 4);
    float4 c3 = *(const float4*)(cf + (size_t)(e + 6) * 4);
    ZPROC(v0, c0); ZPROC(v1, c1); ZPROC(v2, c2); ZPROC(v3, c3);
  }
  for (; e < end; e += 2){
    int s = epk[e] & SRCM;
    uint2 v = *(const uint2*)(xbase + (size_t)s * DD);
    float4 c = *(const float4*)(cf + (size_t)e * 4);
    ZPROC(v, c);
  }
#undef ZPROC
  #pragma unroll
  for (int h = 0; h < 4; h++)
    #pragma unroll
    for (int j = 0; j < 4; j++) acc[h][j] += __shfl_xor(acc[h][j], 32);
  if (ep == 0){
    uint2 v = *(const uint2*)(xbase + (size_t)t * DD);
    float f0 = bflo(v.x), f1 = bfhi(v.x), f2 = bflo(v.y), f3 = bfhi(v.y);
    float4 cs = *(const float4*)(cfS + (size_t)t * 4);
    float4 dn = *(const float4*)(den + (size_t)t * 4);
    const float* csp = (const float*)&cs;
    const float* dnp = (const float*)&dn;
    #pragma unroll
    for (int h = 0; h < 4; h++){
      float sc = 0.25f / dnp[h];
      float y0 = (acc[h][0] + csp[h] * f0) * sc;
      float y1 = (acc[h][1] + csp[h] * f1) * sc;
      float y2 = (acc[h][2] + csp[h] * f2) * sc;
      float y3 = (acc[h][3] + csp[h] * f3) * sc;
      uint2 o; o.x = bfpack(y0, y1); o.y = bfpack(y2, y3);
      *(uint2*)(z + (size_t)t * 512 + h * 128 + dg * 4) = o;
    }
  }
}

// ---------------- MFMA GEMM, 128-row tiles, split-A, fused epilogues (round-12 shape) ------
// MODE 1: Cb = leaky(LN(acc+bias)).  MODE 3: Cf = L2normalize(acc+bias).
template<int MODE>
__launch_bounds__(256)
__global__ void k_gemm_mfma(const __hip_bfloat16* __restrict__ A1, int lda1, int K1,
                            const __hip_bfloat16* __restrict__ A2, int K2,
                            int M, const __hip_bfloat16* __restrict__ Bp, int ntt,
                            const float* __restrict__ bias,
                            const float* __restrict__ ln_g, const float* __restrict__ ln_b,
                            float* __restrict__ Cf, __hip_bfloat16* __restrict__ Cb,
                            int ldc){
  int wave = threadIdx.x >> 6, lane = threadIdx.x & 63;
  int nt0 = blockIdx.y << 3;
  int mbase = blockIdx.x * 128 + wave * 32;
  int r0 = min(mbase + (lane & 15), M - 1);
  int r1 = min(mbase + 16 + (lane & 15), M - 1);
  int koff = (lane >> 4) << 3;
  f32x4 acc[2][8];
  #pragma unroll
  for (int i = 0; i < 2; i++)
    #pragma unroll
    for (int j = 0; j < 8; j++) acc[i][j] = (f32x4){0.f, 0.f, 0.f, 0.f};

  int ktile = 0;
  {
    const __hip_bfloat16* a0p = A1 + (size_t)r0 * lda1 + koff;
    const __hip_bfloat16* a1p = A1 + (size_t)r1 * lda1 + koff;
    for (int k0 = 0; k0 < K1; k0 += 32, ++ktile){
      bf16x8 a0 = *(const bf16x8*)(a0p + k0);
      bf16x8 a1 = *(const bf16x8*)(a1p + k0);
      const bf16x8* bfr = (const bf16x8*)(Bp + (((size_t)ktile * ntt + nt0) * 64 + lane) * 8);
      #pragma unroll
      for (int nt = 0; nt < 8; nt++){
        bf16x8 b = bfr[(size_t)nt * 64];
        acc[0][nt] = __builtin_amdgcn_mfma_f32_16x16x32_bf16(a0, b, acc[0][nt], 0, 0, 0);
        acc[1][nt] = __builtin_amdgcn_mfma_f32_16x16x32_bf16(a1, b, acc[1][nt], 0, 0, 0);
      }
    }
  }
  if (A2){
    const __hip_bfloat16* a0p = A2 + (size_t)r0 * DD + koff;
    const __hip_bfloat16* a1p = A2 + (size_t)r1 * DD + koff;
    for (int k0 = 0; k0 < K2; k0 += 32, ++ktile){
      bf16x8 a0 = *(const bf16x8*)(a0p + k0);
      bf16x8 a1 = *(const bf16x8*)(a1p + k0);
      const bf16x8* bfr = (const bf16x8*)(Bp + (((size_t)ktile * ntt + nt0) * 64 + lane) * 8);
      #pragma unroll
      for (int nt = 0; nt < 8; nt++){
        bf16x8 b = bfr[(size_t)nt * 64];
        acc[0][nt] = __builtin_amdgcn_mfma_f32_16x16x32_bf16(a0, b, acc[0][nt], 0, 0, 0);
        acc[1][nt] = __builtin_amdgcn_mfma_f32_16x16x32_bf16(a1, b, acc[1][nt], 0, 0, 0);
      }
    }
  }

  const int colb = lane & 15;
  const int lq = lane >> 4;

  float bias8[8], g8[8], b8[8];
  #pragma unroll
  for (int nt = 0; nt < 8; nt++){
    int c = (nt << 4) + colb;
    bias8[nt] = bias ? bias[c] : 0.f;
    if (MODE == 1){ g8[nt] = ln_g[c]; b8[nt] = ln_b[c]; }
  }

  #pragma unroll
  for (int mt = 0; mt < 2; mt++){
    #pragma unroll
    for (int j = 0; j < 4; j++){
      int row = mbase + mt * 16 + lq * 4 + j;
      if (MODE == 1){
        float v[8]; float s = 0.f;
        #pragma unroll
        for (int nt = 0; nt < 8; nt++){ v[nt] = acc[mt][nt][j] + bias8[nt]; s += v[nt]; }
        #pragma unroll
        for (int o = 1; o < 16; o <<= 1) s += __shfl_xor(s, o);
        float mu = s * (1.f / 128.f);
        float q = 0.f;
        #pragma unroll
        for (int nt = 0; nt < 8; nt++){ float dd = v[nt] - mu; q += dd * dd; }
        #pragma unroll
        for (int o = 1; o < 16; o <<= 1) q += __shfl_xor(q, o);
        float rstd = rsqrtf(q * (1.f / 128.f) + 1e-5f);
        if (row < M){
          #pragma unroll
          for (int nt = 0; nt < 8; nt++){
            float y = leaky((v[nt] - mu) * rstd * g8[nt] + b8[nt], 0.1f);
            Cb[(size_t)row * ldc + (nt << 4) + colb] = __float2bfloat16(y);
          }
        }
      } else { // MODE 3: bias + L2 normalize, fp32 out
        float v[8]; float q = 0.f;
        #pragma unroll
        for (int nt = 0; nt < 8; nt++){ v[nt] = acc[mt][nt][j] + bias8[nt]; q += v[nt] * v[nt]; }
        #pragma unroll
        for (int o = 1; o < 16; o <<= 1) q += __shfl_xor(q, o);
        float sc = 1.0f / fmaxf(sqrtf(q), 1e-12f);
        if (row < M){
          #pragma unroll
          for (int nt = 0; nt < 8; nt++)
            Cf[(size_t)row * ldc + (nt << 4) + colb] = v[nt] * sc;
        }
      }
    }
  }
}

// ---------------- GAT: per-(dst,head) softmax coefficients ----------------
// Pass 1 gathers aS once and stores LOGITS into cf; pass 2 streams cf (sequential).
__global__ void k_gat_coef(const int* __restrict__ ptr, const int* __restrict__ epk,
                           const float* __restrict__ aS, const float* __restrict__ aD,
                           float* __restrict__ cf, float* __restrict__ cfS,
                           float* __restrict__ den, int N_){
  int id = blockIdx.x * 256 + threadIdx.x;
  int t = id >> 2, h = id & 3;
  if (t >= N_) return;
  int beg = ptr[t * 8], end = ptr[t * 8 + 8];
  float adh = aD[(size_t)t * 4 + h];
  float ash = aS[(size_t)t * 4 + h];
  float selfe = leaky(ash + adh, 0.2f);
  float m = selfe;
  for (int e = beg; e < end; e++){
    int s = epk[e] & SRCM;
    float l = leaky(aS[(size_t)s * 4 + h] + adh, 0.2f);
    cf[(size_t)e * 4 + h] = l;
    m = fmaxf(m, l);
  }
  float sv = __expf(selfe - m);
  cfS[(size_t)t * 4 + h] = sv;
  float d = sv;
  for (int e = beg; e < end; e++){
    float x = __expf(cf[(size_t)e * 4 + h] - m);
    cf[(size_t)e * 4 + h] = x;
    d += x;
  }
  den[(size_t)t * 4 + h] = d;
}

extern "C" void kernel_launch(void* const* d_in, const int* in_sizes, int n_in,
                              void* d_out, int out_size, void* d_ws, size_t ws_size,
                              hipStream_t stream){
  const float* x       = (const float*)d_in[0];
  const int*   ei      = (const int*)d_in[1];
  const int*   et      = (const int*)d_in[2];
  const float* r0_basis= (const float*)d_in[3];  const float* r0_comp = (const float*)d_in[4];
  const float* r0_root = (const float*)d_in[5];  const float* r0_bias = (const float*)d_in[6];
  const float* ln0_g   = (const float*)d_in[7];  const float* ln0_b   = (const float*)d_in[8];
  const float* r1_basis= (const float*)d_in[9];  const float* r1_comp = (const float*)d_in[10];
  const float* r1_root = (const float*)d_in[11]; const float* r1_bias = (const float*)d_in[12];
  const float* ln1_g   = (const float*)d_in[13]; const float* ln1_b   = (const float*)d_in[14];
  const float* gat_w   = (const float*)d_in[15]; const float* gat_asrc= (const float*)d_in[16];
  const float* gat_adst= (const float*)d_in[17]; const float* gat_bias= (const float*)d_in[18];
  const float* ln2_g   = (const float*)d_in[19]; const float* ln2_b   = (const float*)d_in[20];
  const float* r2_basis= (const float*)d_in[21]; const float* r2_comp = (const float*)d_in[22];
  const float* r2_root = (const float*)d_in[23]; const float* r2_bias = (const float*)d_in[24];

  const int N_ = in_sizes[0] / DD;
  const int E_ = in_sizes[2];
  const int NK = N_ * NKEY8;
  const int* src = ei;
  const int* dst = ei + E_;
  float* T2 = (float*)d_out;

  char* wp_ = (char*)d_ws;
  auto alloc = [&](size_t b)->void*{ void* p = wp_; wp_ += (b + 255) & ~(size_t)255; return p; };
  __hip_bfloat16* agg16 = (__hip_bfloat16*)alloc((size_t)N_ * LDA_AGG * 2);  // also hosts z16
  __hip_bfloat16* xb16  = (__hip_bfloat16*)alloc((size_t)N_ * DD * 2);
  float*          inv   = (float*)alloc((size_t)NK * 4);
  int*            ptrb  = (int*)alloc((size_t)(NK + 1) * 4);
  int*            praw  = (int*)alloc((size_t)NK * 4);
  int*            cnt   = (int*)alloc((size_t)NK * 4);
  int*            run   = (int*)alloc((size_t)NK * 4);
  int*            epk   = (int*)alloc((size_t)E_ * 4);
  int*            part  = (int*)alloc(512 * 4);
  float*          aS    = (float*)alloc((size_t)N_ * 4 * 4);
  float*          aD    = (float*)alloc((size_t)N_ * 4 * 4);
  float*          cf    = (float*)alloc((size_t)E_ * 4 * 4);
  float*          cfS   = (float*)alloc((size_t)N_ * 4 * 4);
  float*          den   = (float*)alloc((size_t)N_ * 4 * 4);
  float*          vT    = (float*)alloc((size_t)2 * 512 * 4);
  __hip_bfloat16* Wp0   = (__hip_bfloat16*)alloc((size_t)1152 * 128 * 2);
  __hip_bfloat16* Wp1   = (__hip_bfloat16*)alloc((size_t)1152 * 128 * 2);
  __hip_bfloat16* Wp2   = (__hip_bfloat16*)alloc((size_t)1152 * 128 * 2);
  __hip_bfloat16* WpZ   = (__hip_bfloat16*)alloc((size_t)512 * 128 * 2);
  if ((size_t)(wp_ - (char*)d_ws) > ws_size) return;
  __hip_bfloat16* z16 = agg16;   // aliased: agg dead when z is live, and vice versa

  const int Mb = (N_ + 127) / 128;
  const int nScanB = (NK + 1023) / 1024;
  const int histB = (E_ + 255) / 256;
  const int cvtB  = (N_ * DD + 255) / 256;

  // ---- CSR build (same graph for all layers) + weight prep ----
  hipMemsetAsync(cnt, 0, (size_t)NK * 4, stream);
  k_hist_cvt<<<histB + cvtB, 256, 0, stream>>>(dst, et, cnt, E_, histB, x, xb16, N_ * DD);
  k_scan1<<<nScanB, 256, 0, stream>>>(cnt, praw, part, NK);
  k_scan2<<<1, 512, 0, stream>>>(part, nScanB);
  k_scan3i<<<(NK + 255) / 256, 256, 0, stream>>>(praw, part, ptrb, inv, run, NK, E_);
  k_scatter_pos<<<(E_ + 255) / 256, 256, 0, stream>>>(src, dst, et, run, epk, E_);
  k_prep<<<1988, 256, 0, stream>>>(r0_basis, r0_comp, r0_root,
                                   r1_basis, r1_comp, r1_root,
                                   r2_basis, r2_comp, r2_root,
                                   gat_w, gat_asrc, gat_adst,
                                   Wp0, Wp1, Wp2, WpZ, vT);

  // ---- RGCN layer 0 (LN0+leaky fused) ----
  k_csr_agg<<<(N_ + 7) / 8, 256, 0, stream>>>(ptrb, epk, inv, xb16, agg16, N_);
  k_gemm_mfma<1><<<dim3(Mb, 1), 256, 0, stream>>>(agg16, LDA_AGG, 1024, xb16, 128, N_, Wp0, 8,
      r0_bias, ln0_g, ln0_b, nullptr, xb16, DD);

  // ---- RGCN layer 1 (LN1+leaky fused) ----
  k_csr_agg<<<(N_ + 7) / 8, 256, 0, stream>>>(ptrb, epk, inv, xb16, agg16, N_);
  k_gemm_mfma<1><<<dim3(Mb, 1), 256, 0, stream>>>(agg16, LDA_AGG, 1024, xb16, 128, N_, Wp1, 8,
      r1_bias, ln1_g, ln1_b, nullptr, xb16, DD);

  // ---- GAT: logits from x (no hH), coef, z-aggregate, K=512 GEMM (+bias+LN2 fused) ----
  k_av<<<(N_ + 3) / 4, 256, 0, stream>>>(xb16, vT, aS, aD, N_);
  k_gat_coef<<<(N_ * 4 + 255) / 256, 256, 0, stream>>>(ptrb, epk, aS, aD, cf, cfS, den, N_);
  k_zagg<<<(N_ + 3) / 4, 256, 0, stream>>>(ptrb, epk, cf, cfS, den, xb16, z16, N_);
  k_gemm_mfma<1><<<dim3(Mb, 1), 256, 0, stream>>>(z16, 512, 512, nullptr, 0, N_, WpZ, 8,
      gat_bias, ln2_g, ln2_b, nullptr, xb16, DD);

  // ---- RGCN layer 2 -> d_out (fp32), L2 normalize fused in epilogue ----
  k_csr_agg<<<(N_ + 7) / 8, 256, 0, stream>>>(ptrb, epk, inv, xb16, agg16, N_);
  k_gemm_mfma<3><<<dim3(Mb, 1), 256, 0, stream>>>(agg16, LDA_AGG, 1024, xb16, 128, N_, Wp2, 8,
      r2_bias, nullptr, nullptr, T2, nullptr, DD);
}